// Round 1
// baseline (539.282 us; speedup 1.0000x reference)
//
#include <hip/hip_runtime.h>

// MHA block: LN -> QKV GEMMs (bf16 MFMA) -> flash attention -> proj + residual.
// Workspace layout (assumes ws_size >= ~81 MB):
//   i_ln, o_ln, q, k, vT, ctl : 6 x 8192*768 bf16 (12.58 MB each)
//   Wb: 4 x 768*768 bf16 (Wq,Wk,Wv,Wp)

#define D 768
#define LDP 72            // padded LDS leading dim (bf16 elems); 144 B rows -> conflict-free b128
#define L2E 1.4426950408889634f
#define NW 589824         // 768*768

typedef unsigned int u32;
typedef unsigned short u16;
typedef short bf16x8 __attribute__((ext_vector_type(8)));
typedef float f32x4 __attribute__((ext_vector_type(4)));
typedef u16 u16x4 __attribute__((ext_vector_type(4)));
typedef float f32x4v __attribute__((ext_vector_type(4)));

static __device__ __forceinline__ u16 f2bf(float f) {
  u32 b = __builtin_bit_cast(u32, f);
  b += 0x7FFFu + ((b >> 16) & 1u);   // RNE
  return (u16)(b >> 16);
}

#define MFMA16(a, b, c) __builtin_amdgcn_mfma_f32_16x16x32_bf16((a), (b), (c), 0, 0, 0)

// ---------------- LayerNorm + bf16 cast (both tensors in one launch) ----------------
__global__ __launch_bounds__(256) void ln_kernel(
    const float* __restrict__ icap, const float* __restrict__ ocap,
    const float* __restrict__ g, const float* __restrict__ be,
    u16* __restrict__ iln, u16* __restrict__ oln) {
  int r = blockIdx.x;
  const float* src; u16* dst; int rr;
  if (r < 8192) { src = icap; dst = iln; rr = r; }
  else          { src = ocap; dst = oln; rr = r - 8192; }
  const float* row = src + (size_t)rr * D;
  int t = threadIdx.x;
  float x0 = row[t], x1 = row[t + 256], x2 = row[t + 512];
  float s = x0 + x1 + x2;
  float q = x0 * x0 + x1 * x1 + x2 * x2;
#pragma unroll
  for (int off = 32; off > 0; off >>= 1) {
    s += __shfl_xor(s, off);
    q += __shfl_xor(q, off);
  }
  __shared__ float red[8];
  int w = t >> 6, lane = t & 63;
  if (lane == 0) { red[w] = s; red[4 + w] = q; }
  __syncthreads();
  s = red[0] + red[1] + red[2] + red[3];
  q = red[4] + red[5] + red[6] + red[7];
  float mu = s * (1.0f / 768.0f);
  float var = q * (1.0f / 768.0f) - mu * mu;
  float rs = rsqrtf(var + 1e-5f);
  u16* drow = dst + (size_t)rr * D;
  drow[t]       = f2bf((x0 - mu) * rs * g[t]       + be[t]);
  drow[t + 256] = f2bf((x1 - mu) * rs * g[t + 256] + be[t + 256]);
  drow[t + 512] = f2bf((x2 - mu) * rs * g[t + 512] + be[t + 512]);
}

// ---------------- weight fp32 -> bf16 ----------------
__global__ __launch_bounds__(256) void wcast_kernel(
    const float* __restrict__ w0, const float* __restrict__ w1,
    const float* __restrict__ w2, const float* __restrict__ w3,
    u16* __restrict__ dst) {
  int wsel = blockIdx.y;
  const float* src = wsel == 0 ? w0 : wsel == 1 ? w1 : wsel == 2 ? w2 : w3;
  int i = (blockIdx.x * 256 + threadIdx.x) * 4;
  f32x4v v = *(const f32x4v*)(src + i);
  u16x4 o = { f2bf(v[0]), f2bf(v[1]), f2bf(v[2]), f2bf(v[3]) };
  *(u16x4*)(dst + (size_t)wsel * NW + i) = o;
}

// ---------------- 128x128 GEMM core: C = A[M,768] @ W[768,768]^T ----------------
// A row-major [rows][768] bf16; W row-major [768][768] bf16 (C[m,n] = sum_k A[m,k]*W[n,k]).
// 256 threads = 4 waves, each wave a 64x64 sub-tile (4x4 fragments of 16x16x32).
static __device__ __forceinline__ void gemm_core_128(
    const u16* __restrict__ A, const u16* __restrict__ W,
    int mrow0, int nrow0, f32x4 (&acc)[4][4]) {
  __shared__ __align__(16) u16 As[128][LDP];
  __shared__ __align__(16) u16 Bs[128][LDP];
  const int tid = threadIdx.x;
  const int lane = tid & 63;
  const int w = tid >> 6;
  const int wr = (w >> 1) << 6, wc = (w & 1) << 6;
  const int l15 = lane & 15, lg = lane >> 4;

  for (int kt = 0; kt < D; kt += 64) {
#pragma unroll
    for (int it = 0; it < 4; ++it) {
      int idx = it * 256 + tid;              // 0..1023 -> 128 rows x 8 chunks
      int row = idx >> 3, c8 = (idx & 7) << 3;
      uint4 va = *(const uint4*)(A + (size_t)(mrow0 + row) * D + kt + c8);
      uint4 vb = *(const uint4*)(W + (size_t)(nrow0 + row) * D + kt + c8);
      *(uint4*)&As[row][c8] = va;
      *(uint4*)&Bs[row][c8] = vb;
    }
    __syncthreads();
    bf16x8 af[4][2];
#pragma unroll
    for (int m = 0; m < 4; ++m) {
#pragma unroll
      for (int c = 0; c < 2; ++c)
        af[m][c] = *(const bf16x8*)&As[wr + m * 16 + l15][c * 32 + lg * 8];
    }
#pragma unroll
    for (int n = 0; n < 4; ++n) {
      bf16x8 b0 = *(const bf16x8*)&Bs[wc + n * 16 + l15][lg * 8];
      bf16x8 b1 = *(const bf16x8*)&Bs[wc + n * 16 + l15][32 + lg * 8];
#pragma unroll
      for (int m = 0; m < 4; ++m) {
        acc[m][n] = MFMA16(af[m][0], b0, acc[m][n]);
        acc[m][n] = MFMA16(af[m][1], b1, acc[m][n]);
      }
    }
    __syncthreads();
  }
}

// ---------------- fused Q/K/V GEMM ----------------
// grid (64, 18): y/6 selects 0=q (from o_ln, x0.125), 1=k, 2=v (transposed store to vT)
__global__ __launch_bounds__(256) void qkv_gemm(
    const u16* __restrict__ i_ln, const u16* __restrict__ o_ln,
    const u16* __restrict__ Wb,
    const float* __restrict__ bq, const float* __restrict__ bk,
    const float* __restrict__ bv,
    u16* __restrict__ qout, u16* __restrict__ kout, u16* __restrict__ vT) {
  const int mblk = blockIdx.x;
  const int ny = blockIdx.y;
  const int which = ny / 6;
  const int nb = ny % 6;
  const u16* A = (which == 0) ? o_ln : i_ln;
  const u16* W = Wb + (size_t)which * NW;
  const float* bias = (which == 0) ? bq : (which == 1) ? bk : bv;

  const f32x4 z = {0.f, 0.f, 0.f, 0.f};
  f32x4 acc[4][4];
#pragma unroll
  for (int m = 0; m < 4; ++m)
#pragma unroll
    for (int n = 0; n < 4; ++n) acc[m][n] = z;

  gemm_core_128(A, W, mblk * 128, nb * 128, acc);

  const int lane = threadIdx.x & 63, w = threadIdx.x >> 6;
  const int wr = (w >> 1) << 6, wc = (w & 1) << 6;
  const int l15 = lane & 15, lg = lane >> 4;
  const int m0 = mblk * 128 + wr;
  const int n0 = nb * 128 + wc;

  if (which == 2) {
    // V: store transposed: vT[(b*768 + gn)*4096 + seq], 4 seq-consecutive per frag reg
#pragma unroll
    for (int m = 0; m < 4; ++m) {
#pragma unroll
      for (int n = 0; n < 4; ++n) {
        int gn = n0 + n * 16 + l15;
        float bi = bias[gn];
        int gm = m0 + m * 16 + lg * 4;
        int bidx = gm >> 12, seq = gm & 4095;
        u16x4 pk = { f2bf(acc[m][n][0] + bi), f2bf(acc[m][n][1] + bi),
                     f2bf(acc[m][n][2] + bi), f2bf(acc[m][n][3] + bi) };
        *(u16x4*)(vT + ((size_t)bidx * 768 + gn) * 4096 + seq) = pk;
      }
    }
  } else {
    u16* out = (which == 0) ? qout : kout;
    const float scale = (which == 0) ? 0.125f : 1.0f;  // fold 1/sqrt(64) into q
#pragma unroll
    for (int m = 0; m < 4; ++m) {
#pragma unroll
      for (int n = 0; n < 4; ++n) {
        int gn = n0 + n * 16 + l15;
        float bi = bias[gn];
#pragma unroll
        for (int r = 0; r < 4; ++r) {
          int gm = m0 + m * 16 + lg * 4 + r;
          out[(size_t)gm * D + gn] = f2bf((acc[m][n][r] + bi) * scale);
        }
      }
    }
  }
}

// ---------------- output projection + residual (fp32 out) ----------------
__global__ __launch_bounds__(256) void proj_gemm(
    const u16* __restrict__ ctl, const u16* __restrict__ Wpb,
    const float* __restrict__ bp, const float* __restrict__ res,
    float* __restrict__ out) {
  const int mblk = blockIdx.x;
  const int nb = blockIdx.y;
  const f32x4 z = {0.f, 0.f, 0.f, 0.f};
  f32x4 acc[4][4];
#pragma unroll
  for (int m = 0; m < 4; ++m)
#pragma unroll
    for (int n = 0; n < 4; ++n) acc[m][n] = z;

  gemm_core_128(ctl, Wpb, mblk * 128, nb * 128, acc);

  const int lane = threadIdx.x & 63, w = threadIdx.x >> 6;
  const int wr = (w >> 1) << 6, wc = (w & 1) << 6;
  const int l15 = lane & 15, lg = lane >> 4;
  const int m0 = mblk * 128 + wr;
  const int n0 = nb * 128 + wc;
#pragma unroll
  for (int m = 0; m < 4; ++m) {
#pragma unroll
    for (int n = 0; n < 4; ++n) {
      int gn = n0 + n * 16 + l15;
      float bi = bp[gn];
#pragma unroll
      for (int r = 0; r < 4; ++r) {
        int gm = m0 + m * 16 + lg * 4 + r;
        out[(size_t)gm * D + gn] = res[(size_t)gm * D + gn] + acc[m][n][r] + bi;
      }
    }
  }
}

// ---------------- flash attention ----------------
// grid (32, 24): x = q-tile (128 rows), y = b*12+h. 4 waves x 32 q-rows, KVBLK=64.
__global__ __launch_bounds__(256) void attn_kernel(
    const u16* __restrict__ q, const u16* __restrict__ k,
    const u16* __restrict__ vT, u16* __restrict__ ctl) {
  const int qb = blockIdx.x;
  const int bh = blockIdx.y;
  const int b = bh / 12, h = bh % 12;
  const int tid = threadIdx.x;
  const int lane = tid & 63, w = tid >> 6;
  const int l15 = lane & 15, lg = lane >> 4;

  __shared__ __align__(16) u16 Ks[64][LDP];           // K tile [kv][d]
  __shared__ __align__(16) u16 Vs[64][LDP];           // V^T tile [d][kv]
  __shared__ __align__(16) u16 Ps[4][32][LDP];        // per-wave P [q][kv]

  const int qrow0 = qb * 128 + w * 32;
  const u16* qbase = q + (size_t)b * 4096 * D + h * 64;
  const u16* kbase = k + (size_t)b * 4096 * D + h * 64;
  const u16* vbase = vT + ((size_t)b * 768 + h * 64) * 4096;

  // Q hoisted to registers (already scaled by 0.125 at GEMM time)
  bf16x8 aq[2][2];
#pragma unroll
  for (int mi = 0; mi < 2; ++mi)
#pragma unroll
    for (int c = 0; c < 2; ++c)
      aq[mi][c] = *(const bf16x8*)(qbase + (size_t)(qrow0 + mi * 16 + l15) * D + c * 32 + lg * 8);

  const f32x4 z = {0.f, 0.f, 0.f, 0.f};
  f32x4 acc[2][4];
  float mst[2][4], lst[2][4];
#pragma unroll
  for (int mi = 0; mi < 2; ++mi) {
#pragma unroll
    for (int n = 0; n < 4; ++n) acc[mi][n] = z;
#pragma unroll
    for (int r = 0; r < 4; ++r) { mst[mi][r] = -1e30f; lst[mi][r] = 0.f; }
  }

  for (int kv0 = 0; kv0 < 4096; kv0 += 64) {
    // stage K tile and V^T tile (reg->LDS, padded, conflict-free b128 writes)
#pragma unroll
    for (int it = 0; it < 2; ++it) {
      int idx = it * 256 + tid;          // 0..511 -> 64 rows x 8 chunks
      int row = idx >> 3, c8 = (idx & 7) << 3;
      uint4 vk = *(const uint4*)(kbase + (size_t)(kv0 + row) * D + c8);
      uint4 vv = *(const uint4*)(vbase + (size_t)row * 4096 + kv0 + c8);
      *(uint4*)&Ks[row][c8] = vk;
      *(uint4*)&Vs[row][c8] = vv;
    }
    __syncthreads();

    // S = Q @ K^T  (scores already include 1/8 scale via q)
    f32x4 s[2][4];
#pragma unroll
    for (int mi = 0; mi < 2; ++mi)
#pragma unroll
      for (int t = 0; t < 4; ++t) s[mi][t] = z;
#pragma unroll
    for (int t = 0; t < 4; ++t) {
#pragma unroll
      for (int c = 0; c < 2; ++c) {
        bf16x8 kf = *(const bf16x8*)&Ks[t * 16 + l15][c * 32 + lg * 8];
        s[0][t] = MFMA16(aq[0][c], kf, s[0][t]);
        s[1][t] = MFMA16(aq[1][c], kf, s[1][t]);
      }
    }

    // online softmax (fp32)
#pragma unroll
    for (int mi = 0; mi < 2; ++mi) {
#pragma unroll
      for (int r = 0; r < 4; ++r) {
        float vm = fmaxf(fmaxf(s[mi][0][r], s[mi][1][r]), fmaxf(s[mi][2][r], s[mi][3][r]));
        vm = fmaxf(vm, __shfl_xor(vm, 1));
        vm = fmaxf(vm, __shfl_xor(vm, 2));
        vm = fmaxf(vm, __shfl_xor(vm, 4));
        vm = fmaxf(vm, __shfl_xor(vm, 8));
        float mn = fmaxf(mst[mi][r], vm);
        float es = exp2f((mst[mi][r] - mn) * L2E);
        mst[mi][r] = mn;
        float psum = 0.f;
#pragma unroll
        for (int t = 0; t < 4; ++t) {
          float p = exp2f((s[mi][t][r] - mn) * L2E);
          psum += p;
          Ps[w][mi * 16 + lg * 4 + r][t * 16 + l15] = f2bf(p);
        }
        psum += __shfl_xor(psum, 1);
        psum += __shfl_xor(psum, 2);
        psum += __shfl_xor(psum, 4);
        psum += __shfl_xor(psum, 8);
        lst[mi][r] = lst[mi][r] * es + psum;
#pragma unroll
        for (int n = 0; n < 4; ++n) acc[mi][n][r] *= es;
      }
    }

    // PV: acc += P @ V   (P from per-wave LDS, V^T from shared LDS)
    bf16x8 pa[2][2];
#pragma unroll
    for (int mi = 0; mi < 2; ++mi)
#pragma unroll
      for (int c = 0; c < 2; ++c)
        pa[mi][c] = *(const bf16x8*)&Ps[w][mi * 16 + l15][c * 32 + lg * 8];
#pragma unroll
    for (int n = 0; n < 4; ++n) {
#pragma unroll
      for (int c = 0; c < 2; ++c) {
        bf16x8 vf = *(const bf16x8*)&Vs[n * 16 + l15][c * 32 + lg * 8];
        acc[0][n] = MFMA16(pa[0][c], vf, acc[0][n]);
        acc[1][n] = MFMA16(pa[1][c], vf, acc[1][n]);
      }
    }
    __syncthreads();
  }

  // epilogue: ctl = acc / l
  u16* cbase = ctl + (size_t)b * 4096 * D + h * 64;
#pragma unroll
  for (int mi = 0; mi < 2; ++mi) {
    float inv[4];
#pragma unroll
    for (int r = 0; r < 4; ++r) inv[r] = 1.0f / lst[mi][r];
#pragma unroll
    for (int n = 0; n < 4; ++n) {
#pragma unroll
      for (int r = 0; r < 4; ++r) {
        int row = qrow0 + mi * 16 + lg * 4 + r;
        cbase[(size_t)row * D + n * 16 + l15] = f2bf(acc[mi][n][r] * inv[r]);
      }
    }
  }
}

extern "C" void kernel_launch(void* const* d_in, const int* in_sizes, int n_in,
                              void* d_out, int out_size, void* d_ws, size_t ws_size,
                              hipStream_t stream) {
  const float* in_cap  = (const float*)d_in[0];
  const float* out_cap = (const float*)d_in[1];
  const float* Wq = (const float*)d_in[2];
  const float* bq = (const float*)d_in[3];
  const float* Wk = (const float*)d_in[4];
  const float* bk = (const float*)d_in[5];
  const float* Wv = (const float*)d_in[6];
  const float* bv = (const float*)d_in[7];
  const float* ln_g = (const float*)d_in[8];
  const float* ln_b = (const float*)d_in[9];
  const float* Wp = (const float*)d_in[10];
  const float* bp = (const float*)d_in[11];
  float* out = (float*)d_out;

  char* ws = (char*)d_ws;
  const size_t tsz = (size_t)8192 * D * 2;   // 12,582,912 B
  u16* i_ln = (u16*)(ws + 0 * tsz);
  u16* o_ln = (u16*)(ws + 1 * tsz);
  u16* qb_  = (u16*)(ws + 2 * tsz);
  u16* kb_  = (u16*)(ws + 3 * tsz);
  u16* vT   = (u16*)(ws + 4 * tsz);
  u16* ctl  = (u16*)(ws + 5 * tsz);
  u16* Wb   = (u16*)(ws + 6 * tsz);          // 4 x NW bf16

  ln_kernel<<<dim3(16384), dim3(256), 0, stream>>>(in_cap, out_cap, ln_g, ln_b, i_ln, o_ln);
  wcast_kernel<<<dim3(576, 4), dim3(256), 0, stream>>>(Wq, Wk, Wv, Wp, Wb);
  qkv_gemm<<<dim3(64, 18), dim3(256), 0, stream>>>(i_ln, o_ln, Wb, bq, bk, bv, qb_, kb_, vT);
  attn_kernel<<<dim3(32, 24), dim3(256), 0, stream>>>(qb_, kb_, vT, ctl);
  proj_gemm<<<dim3(64, 6), dim3(256), 0, stream>>>(ctl, Wb + (size_t)3 * NW, bp, out_cap, out);
}

// Round 2
// 343.957 us; speedup vs baseline: 1.5679x; 1.5679x over previous
//
#include <hip/hip_runtime.h>

// MHA block: LN -> QKV GEMMs (bf16 MFMA) -> flash attention -> proj + residual.
// Workspace layout (assumes ws_size >= ~81 MB):
//   i_ln, o_ln, q, k, vT, ctl : 6 x 8192*768 bf16 (12.58 MB each)
//   Wb: 4 x 768*768 bf16 (Wq,Wk,Wv,Wp)

#define D 768
#define LDP 72            // padded LDS leading dim (bf16 elems) for GEMM tiles
#define L2E 1.4426950408889634f
#define NW 589824         // 768*768

typedef unsigned int u32;
typedef unsigned short u16;
typedef short bf16x8 __attribute__((ext_vector_type(8)));
typedef float f32x4 __attribute__((ext_vector_type(4)));
typedef float f32x16 __attribute__((ext_vector_type(16)));
typedef u16 u16x4 __attribute__((ext_vector_type(4)));
typedef u32 u32x4 __attribute__((ext_vector_type(4)));
typedef float f32x4v __attribute__((ext_vector_type(4)));

static __device__ __forceinline__ u16 f2bf(float f) {
  u32 b = __builtin_bit_cast(u32, f);
  b += 0x7FFFu + ((b >> 16) & 1u);   // RNE
  return (u16)(b >> 16);
}

// v_cvt_pk_bf16_f32: word = (bf16(hi)<<16) | bf16(lo)
static __device__ __forceinline__ u32 cvtpk(float lo, float hi) {
  u32 r;
  asm("v_cvt_pk_bf16_f32 %0, %1, %2" : "=v"(r) : "v"(lo), "v"(hi));
  return r;
}

// swap a.lanes[32:63] with b.lanes[0:31]
static __device__ __forceinline__ void plswap(u32& a, u32& b) {
  asm("v_permlane32_swap_b32 %0, %1" : "+v"(a), "+v"(b));
}

#define MFMA16(a, b, c) __builtin_amdgcn_mfma_f32_16x16x32_bf16((a), (b), (c), 0, 0, 0)
#define MFMA32(a, b, c) __builtin_amdgcn_mfma_f32_32x32x16_bf16((a), (b), (c), 0, 0, 0)

// ---------------- LayerNorm + bf16 cast (both tensors in one launch) ----------------
__global__ __launch_bounds__(256) void ln_kernel(
    const float* __restrict__ icap, const float* __restrict__ ocap,
    const float* __restrict__ g, const float* __restrict__ be,
    u16* __restrict__ iln, u16* __restrict__ oln) {
  int r = blockIdx.x;
  const float* src; u16* dst; int rr;
  if (r < 8192) { src = icap; dst = iln; rr = r; }
  else          { src = ocap; dst = oln; rr = r - 8192; }
  const float* row = src + (size_t)rr * D;
  int t = threadIdx.x;
  float x0 = row[t], x1 = row[t + 256], x2 = row[t + 512];
  float s = x0 + x1 + x2;
  float q = x0 * x0 + x1 * x1 + x2 * x2;
#pragma unroll
  for (int off = 32; off > 0; off >>= 1) {
    s += __shfl_xor(s, off);
    q += __shfl_xor(q, off);
  }
  __shared__ float red[8];
  int w = t >> 6, lane = t & 63;
  if (lane == 0) { red[w] = s; red[4 + w] = q; }
  __syncthreads();
  s = red[0] + red[1] + red[2] + red[3];
  q = red[4] + red[5] + red[6] + red[7];
  float mu = s * (1.0f / 768.0f);
  float var = q * (1.0f / 768.0f) - mu * mu;
  float rs = rsqrtf(var + 1e-5f);
  u16* drow = dst + (size_t)rr * D;
  drow[t]       = f2bf((x0 - mu) * rs * g[t]       + be[t]);
  drow[t + 256] = f2bf((x1 - mu) * rs * g[t + 256] + be[t + 256]);
  drow[t + 512] = f2bf((x2 - mu) * rs * g[t + 512] + be[t + 512]);
}

// ---------------- weight fp32 -> bf16 ----------------
__global__ __launch_bounds__(256) void wcast_kernel(
    const float* __restrict__ w0, const float* __restrict__ w1,
    const float* __restrict__ w2, const float* __restrict__ w3,
    u16* __restrict__ dst) {
  int wsel = blockIdx.y;
  const float* src = wsel == 0 ? w0 : wsel == 1 ? w1 : wsel == 2 ? w2 : w3;
  int i = (blockIdx.x * 256 + threadIdx.x) * 4;
  f32x4v v = *(const f32x4v*)(src + i);
  u16x4 o = { f2bf(v[0]), f2bf(v[1]), f2bf(v[2]), f2bf(v[3]) };
  *(u16x4*)(dst + (size_t)wsel * NW + i) = o;
}

// ---------------- 128x128 GEMM core: C = A[M,768] @ W[768,768]^T ----------------
static __device__ __forceinline__ void gemm_core_128(
    const u16* __restrict__ A, const u16* __restrict__ W,
    int mrow0, int nrow0, f32x4 (&acc)[4][4]) {
  __shared__ __align__(16) u16 As[128][LDP];
  __shared__ __align__(16) u16 Bs[128][LDP];
  const int tid = threadIdx.x;
  const int lane = tid & 63;
  const int w = tid >> 6;
  const int wr = (w >> 1) << 6, wc = (w & 1) << 6;
  const int l15 = lane & 15, lg = lane >> 4;

  for (int kt = 0; kt < D; kt += 64) {
#pragma unroll
    for (int it = 0; it < 4; ++it) {
      int idx = it * 256 + tid;              // 0..1023 -> 128 rows x 8 chunks
      int row = idx >> 3, c8 = (idx & 7) << 3;
      uint4 va = *(const uint4*)(A + (size_t)(mrow0 + row) * D + kt + c8);
      uint4 vb = *(const uint4*)(W + (size_t)(nrow0 + row) * D + kt + c8);
      *(uint4*)&As[row][c8] = va;
      *(uint4*)&Bs[row][c8] = vb;
    }
    __syncthreads();
    bf16x8 af[4][2];
#pragma unroll
    for (int m = 0; m < 4; ++m) {
#pragma unroll
      for (int c = 0; c < 2; ++c)
        af[m][c] = *(const bf16x8*)&As[wr + m * 16 + l15][c * 32 + lg * 8];
    }
#pragma unroll
    for (int n = 0; n < 4; ++n) {
      bf16x8 b0 = *(const bf16x8*)&Bs[wc + n * 16 + l15][lg * 8];
      bf16x8 b1 = *(const bf16x8*)&Bs[wc + n * 16 + l15][32 + lg * 8];
#pragma unroll
      for (int m = 0; m < 4; ++m) {
        acc[m][n] = MFMA16(af[m][0], b0, acc[m][n]);
        acc[m][n] = MFMA16(af[m][1], b1, acc[m][n]);
      }
    }
    __syncthreads();
  }
}

// ---------------- fused Q/K/V GEMM ----------------
__global__ __launch_bounds__(256) void qkv_gemm(
    const u16* __restrict__ i_ln, const u16* __restrict__ o_ln,
    const u16* __restrict__ Wb,
    const float* __restrict__ bq, const float* __restrict__ bk,
    const float* __restrict__ bv,
    u16* __restrict__ qout, u16* __restrict__ kout, u16* __restrict__ vT) {
  const int mblk = blockIdx.x;
  const int ny = blockIdx.y;
  const int which = ny / 6;
  const int nb = ny % 6;
  const u16* A = (which == 0) ? o_ln : i_ln;
  const u16* W = Wb + (size_t)which * NW;
  const float* bias = (which == 0) ? bq : (which == 1) ? bk : bv;

  const f32x4 z = {0.f, 0.f, 0.f, 0.f};
  f32x4 acc[4][4];
#pragma unroll
  for (int m = 0; m < 4; ++m)
#pragma unroll
    for (int n = 0; n < 4; ++n) acc[m][n] = z;

  gemm_core_128(A, W, mblk * 128, nb * 128, acc);

  const int lane = threadIdx.x & 63, w = threadIdx.x >> 6;
  const int wr = (w >> 1) << 6, wc = (w & 1) << 6;
  const int l15 = lane & 15, lg = lane >> 4;
  const int m0 = mblk * 128 + wr;
  const int n0 = nb * 128 + wc;

  if (which == 2) {
#pragma unroll
    for (int m = 0; m < 4; ++m) {
#pragma unroll
      for (int n = 0; n < 4; ++n) {
        int gn = n0 + n * 16 + l15;
        float bi = bias[gn];
        int gm = m0 + m * 16 + lg * 4;
        int bidx = gm >> 12, seq = gm & 4095;
        u16x4 pk = { f2bf(acc[m][n][0] + bi), f2bf(acc[m][n][1] + bi),
                     f2bf(acc[m][n][2] + bi), f2bf(acc[m][n][3] + bi) };
        *(u16x4*)(vT + ((size_t)bidx * 768 + gn) * 4096 + seq) = pk;
      }
    }
  } else {
    u16* out = (which == 0) ? qout : kout;
    const float scale = (which == 0) ? 0.125f : 1.0f;  // fold 1/sqrt(64) into q
#pragma unroll
    for (int m = 0; m < 4; ++m) {
#pragma unroll
      for (int n = 0; n < 4; ++n) {
        int gn = n0 + n * 16 + l15;
        float bi = bias[gn];
#pragma unroll
        for (int r = 0; r < 4; ++r) {
          int gm = m0 + m * 16 + lg * 4 + r;
          out[(size_t)gm * D + gn] = f2bf((acc[m][n][r] + bi) * scale);
        }
      }
    }
  }
}

// ---------------- output projection + residual (fp32 out) ----------------
__global__ __launch_bounds__(256) void proj_gemm(
    const u16* __restrict__ ctl, const u16* __restrict__ Wpb,
    const float* __restrict__ bp, const float* __restrict__ res,
    float* __restrict__ out) {
  const int mblk = blockIdx.x;
  const int nb = blockIdx.y;
  const f32x4 z = {0.f, 0.f, 0.f, 0.f};
  f32x4 acc[4][4];
#pragma unroll
  for (int m = 0; m < 4; ++m)
#pragma unroll
    for (int n = 0; n < 4; ++n) acc[m][n] = z;

  gemm_core_128(ctl, Wpb, mblk * 128, nb * 128, acc);

  const int lane = threadIdx.x & 63, w = threadIdx.x >> 6;
  const int wr = (w >> 1) << 6, wc = (w & 1) << 6;
  const int l15 = lane & 15, lg = lane >> 4;
  const int m0 = mblk * 128 + wr;
  const int n0 = nb * 128 + wc;
#pragma unroll
  for (int m = 0; m < 4; ++m) {
#pragma unroll
    for (int n = 0; n < 4; ++n) {
      int gn = n0 + n * 16 + l15;
      float bi = bp[gn];
#pragma unroll
      for (int r = 0; r < 4; ++r) {
        int gm = m0 + m * 16 + lg * 4 + r;
        out[(size_t)gm * D + gn] = res[(size_t)gm * D + gn] + acc[m][n][r] + bi;
      }
    }
  }
}

// ---------------- flash attention: swapped-QK^T, lane-local softmax ----------------
// grid (32, 24): x = q-tile (128 rows), y = b*12+h. 4 waves x 32 q-rows, KVBLK=64.
// S^T = mfma32(K, Q): lane owns q = lane&31; regs hold kv = (r&3)+8*(r>>2)+4*hi.
// PV (swapped): O^T = mfma32(V^T, P^T) -> lane still owns its q column.
__global__ __launch_bounds__(256, 3) void attn_kernel(
    const u16* __restrict__ q, const u16* __restrict__ k,
    const u16* __restrict__ vT, u16* __restrict__ ctl) {
  const int qb = blockIdx.x;
  const int bh = blockIdx.y;
  const int b = bh / 12, h = bh % 12;
  const int tid = threadIdx.x;
  const int lane = tid & 63, w = tid >> 6;
  const int l31 = lane & 31;
  const int hi = lane >> 5;        // 0/1: which 32-lane half
  const int swz = l31 & 7;         // XOR swizzle key (row & 7)

  __shared__ __align__(16) u16 Ks[64 * 64];   // K tile [kv][d], 16B-chunk-swizzled
  __shared__ __align__(16) u16 Vs[64 * 64];   // V^T tile [d][kv], same swizzle

  const int qrow0 = qb * 128 + w * 32;
  const u16* qbase = q + (size_t)b * 4096 * D + h * 64;
  const u16* kbase = k + (size_t)b * 4096 * D + h * 64;
  const u16* vbase = vT + ((size_t)b * 768 + h * 64) * 4096;

  // Q fragments (B-operand): qf[ks][jj] = Q[q=l31][16*ks + 8*hi + jj]
  bf16x8 qf[4];
#pragma unroll
  for (int ks = 0; ks < 4; ++ks)
    qf[ks] = *(const bf16x8*)(qbase + (size_t)(qrow0 + l31) * D + ks * 16 + hi * 8);

  f32x16 acc[2];
#pragma unroll
  for (int db = 0; db < 2; ++db)
#pragma unroll
    for (int r = 0; r < 16; ++r) acc[db][r] = 0.f;
  float m = -1e30f, l = 0.f;

  for (int kv0 = 0; kv0 < 4096; kv0 += 64) {
    // stage K and V^T tiles (coalesced global -> swizzled LDS)
#pragma unroll
    for (int it = 0; it < 2; ++it) {
      int idx = it * 256 + tid;          // 0..511 -> 64 rows x 8 chunks of 16B
      int row = idx >> 3, c16 = idx & 7;
      int sc = c16 ^ (row & 7);
      uint4 vk = *(const uint4*)(kbase + (size_t)(kv0 + row) * D + c16 * 8);
      uint4 vv = *(const uint4*)(vbase + (size_t)row * 4096 + kv0 + c16 * 8);
      *(uint4*)&Ks[row * 64 + sc * 8] = vk;
      *(uint4*)&Vs[row * 64 + sc * 8] = vv;
    }
    __syncthreads();

    // S^T = K @ Q^T  (q pre-scaled by 1/8)
    f32x16 st[2];
#pragma unroll
    for (int t = 0; t < 2; ++t) {
      f32x16 s;
#pragma unroll
      for (int r = 0; r < 16; ++r) s[r] = 0.f;
#pragma unroll
      for (int ks = 0; ks < 4; ++ks) {
        bf16x8 kf = *(const bf16x8*)&Ks[(t * 32 + l31) * 64 + ((2 * ks + hi) ^ swz) * 8];
        s = MFMA32(kf, qf[ks], s);
      }
      st[t] = s;
    }

    // lane-local online softmax (lane owns one q row; partner lane^32 has other half)
    float pm = st[0][0];
#pragma unroll
    for (int t = 0; t < 2; ++t)
#pragma unroll
      for (int r = 0; r < 16; ++r) pm = fmaxf(pm, st[t][r]);
    { u32 a = __builtin_bit_cast(u32, pm), bb = a;
      plswap(a, bb);
      float po = __builtin_bit_cast(float, hi ? a : bb);
      pm = fmaxf(pm, po); }

    if (pm > m + 8.0f) {               // defer-max (T13): rescale only on big jump
      float es = __builtin_amdgcn_exp2f((m - pm) * L2E);
      m = pm;
      l *= es;
#pragma unroll
      for (int db = 0; db < 2; ++db)
#pragma unroll
        for (int r = 0; r < 16; ++r) acc[db][r] *= es;
    }
    float mL2 = m * L2E;

    float ls = 0.f;
    bf16x8 pf[4];
#pragma unroll
    for (int t = 0; t < 2; ++t) {
      float p[16];
#pragma unroll
      for (int r = 0; r < 16; ++r) {
        p[r] = __builtin_amdgcn_exp2f(st[t][r] * L2E - mL2);
        ls += p[r];
      }
      // pack to bf16 PV B-fragments: frag[2t] = kv 16t*2..+15, frag[2t+1] = next 16
      u32 a0 = cvtpk(p[0], p[1]),   a1 = cvtpk(p[2], p[3]);
      u32 b0 = cvtpk(p[4], p[5]),   b1 = cvtpk(p[6], p[7]);
      plswap(a0, b0); plswap(a1, b1);
      u32x4 w0 = {a0, a1, b0, b1};
      pf[2 * t] = __builtin_bit_cast(bf16x8, w0);
      u32 c0 = cvtpk(p[8], p[9]),   c1 = cvtpk(p[10], p[11]);
      u32 d0 = cvtpk(p[12], p[13]), d1 = cvtpk(p[14], p[15]);
      plswap(c0, d0); plswap(c1, d1);
      u32x4 w1 = {c0, c1, d0, d1};
      pf[2 * t + 1] = __builtin_bit_cast(bf16x8, w1);
    }
    { u32 a = __builtin_bit_cast(u32, ls), bb = a;
      plswap(a, bb);
      float lo = __builtin_bit_cast(float, hi ? a : bb);
      ls += lo; }
    l += ls;

    // O^T += V^T @ P^T
#pragma unroll
    for (int db = 0; db < 2; ++db)
#pragma unroll
      for (int ks = 0; ks < 4; ++ks) {
        bf16x8 vf = *(const bf16x8*)&Vs[(db * 32 + l31) * 64 + ((2 * ks + hi) ^ swz) * 8];
        acc[db] = MFMA32(vf, pf[ks], acc[db]);
      }
    __syncthreads();
  }

  // epilogue: ctl[q][h*64 + d] = acc/l ; d = (r&3) + 8*(r>>2) + 4*hi + 32*db
  float inv = 1.0f / l;
  u16* cbase = ctl + ((size_t)b * 4096 + qrow0 + l31) * D + h * 64;
#pragma unroll
  for (int db = 0; db < 2; ++db)
#pragma unroll
    for (int rq = 0; rq < 4; ++rq) {
      u16x4 pkv = { f2bf(acc[db][rq * 4 + 0] * inv), f2bf(acc[db][rq * 4 + 1] * inv),
                    f2bf(acc[db][rq * 4 + 2] * inv), f2bf(acc[db][rq * 4 + 3] * inv) };
      *(u16x4*)(cbase + db * 32 + rq * 8 + hi * 4) = pkv;
    }
}

extern "C" void kernel_launch(void* const* d_in, const int* in_sizes, int n_in,
                              void* d_out, int out_size, void* d_ws, size_t ws_size,
                              hipStream_t stream) {
  const float* in_cap  = (const float*)d_in[0];
  const float* out_cap = (const float*)d_in[1];
  const float* Wq = (const float*)d_in[2];
  const float* bq = (const float*)d_in[3];
  const float* Wk = (const float*)d_in[4];
  const float* bk = (const float*)d_in[5];
  const float* Wv = (const float*)d_in[6];
  const float* bv = (const float*)d_in[7];
  const float* ln_g = (const float*)d_in[8];
  const float* ln_b = (const float*)d_in[9];
  const float* Wp = (const float*)d_in[10];
  const float* bp = (const float*)d_in[11];
  float* out = (float*)d_out;

  char* ws = (char*)d_ws;
  const size_t tsz = (size_t)8192 * D * 2;   // 12,582,912 B
  u16* i_ln = (u16*)(ws + 0 * tsz);
  u16* o_ln = (u16*)(ws + 1 * tsz);
  u16* qb_  = (u16*)(ws + 2 * tsz);
  u16* kb_  = (u16*)(ws + 3 * tsz);
  u16* vT   = (u16*)(ws + 4 * tsz);
  u16* ctl  = (u16*)(ws + 5 * tsz);
  u16* Wb   = (u16*)(ws + 6 * tsz);          // 4 x NW bf16

  ln_kernel<<<dim3(16384), dim3(256), 0, stream>>>(in_cap, out_cap, ln_g, ln_b, i_ln, o_ln);
  wcast_kernel<<<dim3(576, 4), dim3(256), 0, stream>>>(Wq, Wk, Wv, Wp, Wb);
  qkv_gemm<<<dim3(64, 18), dim3(256), 0, stream>>>(i_ln, o_ln, Wb, bq, bk, bv, qb_, kb_, vT);
  attn_kernel<<<dim3(32, 24), dim3(256), 0, stream>>>(qb_, kb_, vT, ctl);
  proj_gemm<<<dim3(64, 6), dim3(256), 0, stream>>>(ctl, Wb + (size_t)3 * NW, bp, out_cap, out);
}